// Round 15
// baseline (535.212 us; speedup 1.0000x reference)
//
#include <hip/hip_runtime.h>

#define T 512
constexpr int Bc = 512, Nc = 40, Hc = 128, FEc = 16, Mc = 128, OUTc = 128, NPASS = 3;
constexpr int ROWP = 136;   // bf16 LDS row pitch (MFMA A buffers: aligned b128 reads)
constexpr int NPP  = 132;   // scalar-access row pitch (np fp32 / emb bf16 / r / z)
constexpr int EPOOL = 320;  // LDS edge pool slots (mean ~296; ~14% of blocks spill a few edges to fallback)

typedef __attribute__((ext_vector_type(8))) short short8;
typedef __attribute__((ext_vector_type(4))) float floatx4;
typedef __attribute__((ext_vector_type(4))) float fvec4;
typedef _Float16 half2v __attribute__((ext_vector_type(2)));
typedef _Float16 half8v __attribute__((ext_vector_type(8)));

// ws layout (bf16 elements): fragment-major B operands only (384 KB, L2-resident)
constexpr int WS_WN = 0, WS_WM = 16384, WS_WI = 32768, WS_WH = 81920, WS_WG = 131072, WS_WO = 163840;

__device__ __forceinline__ float fast_rcp(float x) { return __builtin_amdgcn_rcpf(x); }
__device__ __forceinline__ float fast_sigmoid(float x) { return fast_rcp(1.f + __expf(-x)); }
__device__ __forceinline__ float fast_tanh(float x) {
    float t = __expf(2.f * x);
    return 1.f - 2.f * fast_rcp(t + 1.f);
}
__device__ __forceinline__ float bf2f(unsigned short u) {
    union { unsigned int i; float f; } v; v.i = ((unsigned int)u) << 16; return v.f;
}
__device__ __forceinline__ unsigned short f2bf(float f) {
    union { float f; unsigned int i; } v; v.f = f;
    unsigned int r = v.i + 0x7fff + ((v.i >> 16) & 1);   // RNE
    return (unsigned short)(r >> 16);
}
__device__ __forceinline__ half2v u2h(unsigned int u) {
    union { unsigned int i; half2v h; } v; v.i = u; return v.h;
}

__device__ __forceinline__ floatx4 mm(short8 a, short8 b, floatx4 c) {
    return __builtin_amdgcn_mfma_f32_16x16x32_bf16(a, b, c, 0, 0, 0);
}
// A-fragment: A[m=lane&15][k=quad*8+j]; rows>=40 clamped (their C rows discarded)
__device__ __forceinline__ short8 afrag(const unsigned short* buf, int mt, int kt, int lane) {
    int row = mt * 16 + (lane & 15); row = row > 39 ? 39 : row;
    return *(const short8*)(buf + row * ROWP + kt * 32 + (lane >> 4) * 8);
}
__device__ __forceinline__ short8 bfrag(const unsigned short* w, int nt, int nKT, int kt, int lane) {
    return *(const short8*)(w + ((nt * nKT + kt) * 64 + lane) * 8);
}

// ---- prep: weights -> bf16 B-fragment layout in ws ----
__global__ void prep_kernel(const float* __restrict__ Wn, const float* __restrict__ Wm,
                            const float* __restrict__ Wi, const float* __restrict__ Wh,
                            const float* __restrict__ Wg, const float* __restrict__ Wo,
                            unsigned short* __restrict__ ws) {
    int c = blockIdx.x, lane = threadIdx.x;
    int quad = lane >> 4, l16 = lane & 15;
    const float* W; int N, nKT, local; unsigned short* dst;
    if (c < 32)       { W = Wn; N = 128; nKT = 4; local = c;       dst = ws + WS_WN; }
    else if (c < 64)  { W = Wm; N = 128; nKT = 4; local = c - 32;  dst = ws + WS_WM; }
    else if (c < 160) { W = Wi; N = 384; nKT = 4; local = c - 64;  dst = ws + WS_WI; }
    else if (c < 256) { W = Wh; N = 384; nKT = 4; local = c - 160; dst = ws + WS_WH; }
    else if (c < 320) { W = Wg; N = 128; nKT = 8; local = c - 256; dst = ws + WS_WG; }
    else              { W = Wo; N = 128; nKT = 8; local = c - 320; dst = ws + WS_WO; }
    int nt = local / nKT, kt = local % nKT;
    short8 v;
#pragma unroll
    for (int j = 0; j < 8; ++j) {
        int k = kt * 32 + quad * 8 + j;
        v[j] = (short)f2bf(W[k * N + nt * 16 + l16]);
    }
    *(short8*)(dst + local * 512 + lane * 8) = v;
}

// T=512, 8 waves, LDS ~77 KB -> 2 blocks/CU.
// Anti-spill rules (R9/R10/R12): attention reads LDS only; GEMM kt loops unroll 1 with
// inline bfrag (NO hoist — R14 spilled); no per-thread state across barriers.
// R15: h double-buffer (beta writes next buffer -> 1 fewer barrier/pass, no commit
// loop); LPT snake-balanced attention rows; jo offset table.
__global__ __launch_bounds__(T, 4) void mpnn_kernel(
    const float* __restrict__ nodes, const float* __restrict__ edges,
    const float* __restrict__ We, const float* __restrict__ bi,
    const float* __restrict__ bh, const float* __restrict__ bg,
    const float* __restrict__ bo, const unsigned short* __restrict__ ws,
    float* __restrict__ out)
{
    __shared__ __attribute__((aligned(16))) unsigned short s_hbA[Nc * ROWP];  // bf16 h (buffer A)
    __shared__ __attribute__((aligned(16))) unsigned short s_hbB[Nc * ROWP];  // bf16 h (buffer B)
    __shared__ __attribute__((aligned(16))) unsigned short s_mb[Nc * ROWP];   // messages / nodes(cat)
    __shared__ __attribute__((aligned(16))) float s_np[Nc * NPP];             // np fp32, then r (init: slot_src)
    __shared__ __attribute__((aligned(16))) unsigned short s_ebb[Nc * NPP];   // emb bf16, then z
    __shared__ __attribute__((aligned(16))) _Float16 s_poolh[EPOOL * FEc];    // 10 KB f16 edge features
    __shared__ unsigned short s_jo[EPOOL];   // per-slot j*NPP (element offset for np/emb)
    __shared__ unsigned char s_nbr[Nc][Nc];
    __shared__ unsigned char s_rowmap[4][10]; // LPT snake row assignment per g-group
    __shared__ int s_cnt[Nc];
    __shared__ int s_off[Nc];
    __shared__ int s_total;

    const int b = blockIdx.x, tid = threadIdx.x;
    const int lane = tid & 63, wave = tid >> 6;          // 8 waves; nt = wave
    const int quad = lane >> 4, l16 = lane & 15;
    const int m = tid & 127, g = tid >> 7;               // attention: g in 0..3
    const int col = wave * 16 + l16;

    const float* nodes_b = nodes + (size_t)b * Nc * Hc;
    const float* edges_b = edges + (size_t)b * Nc * Nc * FEc;
    const unsigned short* wWn = ws + WS_WN; const unsigned short* wWm = ws + WS_WM;
    const unsigned short* wWi = ws + WS_WI; const unsigned short* wWh = ws + WS_WH;
    const unsigned short* wWg = ws + WS_WG; const unsigned short* wWo = ws + WS_WO;

    // ---- init: h fp32 in registers (static map, fully unrolled), bf16 in LDS (A) ----
    float hreg[3][4];
#pragma unroll
    for (int mt = 0; mt < 3; ++mt)
#pragma unroll
        for (int reg = 0; reg < 4; ++reg) {
            int row = mt * 16 + quad * 4 + reg;
            float v = (row < Nc) ? nodes_b[row * Hc + col] : 0.f;
            hreg[mt][reg] = v;
            if (row < Nc) s_hbA[row * ROWP + col] = f2bf(v);
        }
    // ---- adjacency scan (streaming, non-temporal) ----
    for (int p = tid; p < Nc * Nc; p += T) {
        const fvec4* e4 = (const fvec4*)(edges_b + p * FEc);
        fvec4 a0 = __builtin_nontemporal_load(e4);
        fvec4 a1 = __builtin_nontemporal_load(e4 + 1);
        fvec4 a2 = __builtin_nontemporal_load(e4 + 2);
        fvec4 a3 = __builtin_nontemporal_load(e4 + 3);
        float s = a0.x + a0.y + a0.z + a0.w + a1.x + a1.y + a1.z + a1.w
                + a2.x + a2.y + a2.z + a2.w + a3.x + a3.y + a3.z + a3.w;
        ((unsigned char*)s_nbr)[p] = (s > 0.f) ? 1 : 0;
    }
    __syncthreads();
    if (tid < Nc) {               // compact neighbor list in place
        int c = 0;
#pragma unroll 1
        for (int j = 0; j < Nc; ++j)
            if (s_nbr[tid][j]) { s_nbr[tid][c] = (unsigned char)j; ++c; }
        s_cnt[tid] = c;
    }
    __syncthreads();
    if (tid == 0) {
        int tot = 0;
#pragma unroll 1
        for (int i = 0; i < Nc; ++i) { s_off[i] = tot; tot += s_cnt[i]; }
        s_total = tot;
        // LPT snake balancing: sort rows by cnt desc, snake-assign to 4 groups
        unsigned char srt[Nc];
#pragma unroll 1
        for (int i = 0; i < Nc; ++i) srt[i] = (unsigned char)i;
#pragma unroll 1
        for (int a = 1; a < Nc; ++a) {       // insertion sort desc by cnt
            unsigned char key = srt[a];
            int kc = s_cnt[key], p2 = a - 1;
#pragma unroll 1
            while (p2 >= 0 && s_cnt[srt[p2]] < kc) { srt[p2 + 1] = srt[p2]; --p2; }
            srt[p2 + 1] = key;
        }
        int pos[4] = {0, 0, 0, 0};
#pragma unroll 1
        for (int k = 0; k < Nc; ++k) {
            int idx = k & 3;
            int gg = ((k >> 2) & 1) ? (3 - idx) : idx;   // snake
            s_rowmap[gg][pos[gg]++] = srt[k];
        }
    }
    __syncthreads();
    int* slot_src = (int*)s_np;   // temp alias; dead before pass-0 Phase A writes s_np
    if (tid < Nc) {
        int base = s_off[tid], cnt = s_cnt[tid];
#pragma unroll 1
        for (int kn = 0; kn < cnt; ++kn) {
            int slot = base + kn;
            if (slot < EPOOL) {
                int j = s_nbr[tid][kn];
                slot_src[slot] = tid * Nc + j;
                s_jo[slot] = (unsigned short)(j * NPP);
            }
        }
    }
    __syncthreads();
    {   // fill compact f16 edge pool (once; reused all 3 passes)
        const int E = s_total < EPOOL ? s_total : EPOOL;
#pragma unroll 1
        for (int w = tid; w < E * 2; w += T) {
            int s = w >> 1, hf = w & 1;
            const float* src = edges_b + (size_t)slot_src[s] * FEc + hf * 8;
            fvec4 x = __builtin_nontemporal_load((const fvec4*)src);
            fvec4 y = __builtin_nontemporal_load((const fvec4*)(src + 4));
            half8v v;
            v[0] = (_Float16)x.x; v[1] = (_Float16)x.y; v[2] = (_Float16)x.z; v[3] = (_Float16)x.w;
            v[4] = (_Float16)y.x; v[5] = (_Float16)y.y; v[6] = (_Float16)y.z; v[7] = (_Float16)y.w;
            *(half8v*)(s_poolh + s * FEc + hf * 8) = v;
        }
    }
    __syncthreads();

    unsigned short* hb_cur = s_hbA;
    unsigned short* hb_nxt = s_hbB;

    for (int pass = 0; pass < NPASS; ++pass) {
        // ---- Phase A: np = h@Wn (fp32), emb = h@Wm (bf16) ----
#pragma unroll 1
        for (int jb = 0; jb < 2; ++jb) {
            const unsigned short* wb = jb ? wWm : wWn;
            short8 bfr[4];
#pragma unroll
            for (int kt = 0; kt < 4; ++kt) bfr[kt] = bfrag(wb, wave, 4, kt, lane);
#pragma unroll 1
            for (int mt = 0; mt < 3; ++mt) {
                floatx4 acc = {0.f, 0.f, 0.f, 0.f};
#pragma unroll
                for (int kt = 0; kt < 4; ++kt) acc = mm(afrag(hb_cur, mt, kt, lane), bfr[kt], acc);
#pragma unroll
                for (int reg = 0; reg < 4; ++reg) {
                    int row = mt * 16 + quad * 4 + reg;
                    if (row < Nc) {
                        if (jb) s_ebb[row * NPP + col] = f2bf(acc[reg]);
                        else    s_np[row * NPP + col] = acc[reg];
                    }
                }
            }
        }
        __syncthreads();

        // ---- Attention: f16 pool + fdot2, jo-table, LPT-balanced rows ----
        {
#if __has_builtin(__builtin_amdgcn_fdot2)
            half2v wh[8];
#pragma unroll
            for (int f = 0; f < 8; ++f)
                wh[f] = (half2v){(_Float16)We[(2 * f) * Mc + m], (_Float16)We[(2 * f + 1) * Mc + m]};
#else
            float wef[FEc];
#pragma unroll
            for (int f = 0; f < FEc; ++f) wef[f] = We[f * Mc + m];
#endif
#pragma unroll 1
            for (int ib = 0; ib < 10; ++ib) {
                int i = s_rowmap[g][ib];
                int cnt = s_cnt[i], base = s_off[i];
                int cap = EPOOL - base; if (cap > cnt) cap = cnt; if (cap < 0) cap = 0;
                float pden = 0.f, pnum = 0.f;
#pragma unroll 1
                for (int s = base; s < base + cap; ++s) {
                    const uint4* e = (const uint4*)(s_poolh + s * FEc);
                    uint4 p0 = e[0], p1 = e[1];
                    int jo = s_jo[s];
                    float np = s_np[jo + m];
                    float em = bf2f(s_ebb[jo + m]);
#if __has_builtin(__builtin_amdgcn_fdot2)
                    float ep = 0.f;
                    ep = __builtin_amdgcn_fdot2(u2h(p0.x), wh[0], ep, false);
                    ep = __builtin_amdgcn_fdot2(u2h(p0.y), wh[1], ep, false);
                    ep = __builtin_amdgcn_fdot2(u2h(p0.z), wh[2], ep, false);
                    ep = __builtin_amdgcn_fdot2(u2h(p0.w), wh[3], ep, false);
                    ep = __builtin_amdgcn_fdot2(u2h(p1.x), wh[4], ep, false);
                    ep = __builtin_amdgcn_fdot2(u2h(p1.y), wh[5], ep, false);
                    ep = __builtin_amdgcn_fdot2(u2h(p1.z), wh[6], ep, false);
                    ep = __builtin_amdgcn_fdot2(u2h(p1.w), wh[7], ep, false);
#else
                    half2v h0 = u2h(p0.x), h1 = u2h(p0.y), h2 = u2h(p0.z), h3 = u2h(p0.w);
                    half2v h4 = u2h(p1.x), h5 = u2h(p1.y), h6 = u2h(p1.z), h7 = u2h(p1.w);
                    float ep = (float)h0.x*wef[0] + (float)h0.y*wef[1] + (float)h1.x*wef[2] + (float)h1.y*wef[3]
                             + (float)h2.x*wef[4] + (float)h2.y*wef[5] + (float)h3.x*wef[6] + (float)h3.y*wef[7]
                             + (float)h4.x*wef[8] + (float)h4.y*wef[9] + (float)h5.x*wef[10]+ (float)h5.y*wef[11]
                             + (float)h6.x*wef[12]+ (float)h6.y*wef[13]+ (float)h7.x*wef[14]+ (float)h7.y*wef[15];
#endif
                    float w = __expf(fast_tanh(ep + np));   // logits in (-1,1): no max-sub
                    pden += w;
                    pnum += w * em;
                }
#pragma unroll 1
                for (int kn = cap; kn < cnt; ++kn) {   // pool-overflow tail (rare)
                    int j = s_nbr[i][kn];
                    const float4* ef = (const float4*)(edges_b + ((size_t)i * Nc + j) * FEc);
                    float4 a0 = ef[0], a1 = ef[1], a2 = ef[2], a3 = ef[3];
                    float ep = a0.x*We[0*Mc+m] + a0.y*We[1*Mc+m] + a0.z*We[2*Mc+m] + a0.w*We[3*Mc+m]
                             + a1.x*We[4*Mc+m] + a1.y*We[5*Mc+m] + a1.z*We[6*Mc+m] + a1.w*We[7*Mc+m]
                             + a2.x*We[8*Mc+m] + a2.y*We[9*Mc+m] + a2.z*We[10*Mc+m]+ a2.w*We[11*Mc+m]
                             + a3.x*We[12*Mc+m]+ a3.y*We[13*Mc+m]+ a3.z*We[14*Mc+m]+ a3.w*We[15*Mc+m];
                    float np = s_np[j * NPP + m];
                    float em = bf2f(s_ebb[j * NPP + m]);
                    float w = __expf(fast_tanh(ep + np));
                    pden += w;
                    pnum += w * em;
                }
                s_mb[i * ROWP + m] = f2bf((cnt > 0) ? pnum * fast_rcp(pden) : 0.f);
            }
        }
        __syncthreads();

        // ---- GRU alpha: r (fp32 s_np), z (bf16 s_ebb); inline bfrag, 1 acc set ----
#pragma unroll 1
        for (int grp = 0; grp < 2; ++grp) {
            float bb = bi[grp * 128 + col] + bh[grp * 128 + col];
#pragma unroll 1
            for (int mt = 0; mt < 3; ++mt) {
                floatx4 acc = {0.f,0.f,0.f,0.f};
#pragma unroll 1
                for (int kt = 0; kt < 4; ++kt) {
                    acc = mm(afrag(s_mb, mt, kt, lane), bfrag(wWi, grp * 8 + wave, 4, kt, lane), acc);
                    acc = mm(afrag(hb_cur, mt, kt, lane), bfrag(wWh, grp * 8 + wave, 4, kt, lane), acc);
                }
#pragma unroll
                for (int reg = 0; reg < 4; ++reg) {
                    int row = mt * 16 + quad * 4 + reg;
                    if (row < Nc) {
                        float sg = fast_sigmoid(acc[reg] + bb);
                        if (grp) s_ebb[row * NPP + col] = f2bf(sg);
                        else     s_np[row * NPP + col] = sg;
                    }
                }
            }
        }
        // ---- GRU beta: candidate + h update -> hreg AND next h buffer (no commit loop) ----
        {
            float bnI = bi[256 + col], bnH = bh[256 + col];
#pragma unroll
            for (int mt = 0; mt < 3; ++mt) {
                floatx4 ai = {0.f,0.f,0.f,0.f}, ah = {0.f,0.f,0.f,0.f};
#pragma unroll 1
                for (int kt = 0; kt < 4; ++kt) {
                    ai = mm(afrag(s_mb, mt, kt, lane), bfrag(wWi, 16 + wave, 4, kt, lane), ai);
                    ah = mm(afrag(hb_cur, mt, kt, lane), bfrag(wWh, 16 + wave, 4, kt, lane), ah);
                }
#pragma unroll
                for (int reg = 0; reg < 4; ++reg) {
                    int row = mt * 16 + quad * 4 + reg;
                    if (row < Nc) {
                        float hold = hreg[mt][reg];
                        float r = s_np[row * NPP + col];
                        float z = bf2f(s_ebb[row * NPP + col]);
                        float n = fast_tanh(ai[reg] + bnI + r * (ah[reg] + bnH));
                        float v = (1.f - z) * n + z * hold;
                        v = (s_cnt[row] > 0) ? v : hold;
                        hreg[mt][reg] = v;
                        hb_nxt[row * ROWP + col] = f2bf(v);   // next buffer: no reader this pass
                    }
                }
            }
        }
        __syncthreads();   // writes to hb_nxt + all reads of hb_cur complete
        unsigned short* tmp = hb_cur; hb_cur = hb_nxt; hb_nxt = tmp;
    }

    // ---- Readout: out = sum_i mask * sigmoid(cat@Wg+bg) * (cat@Wo+bo) ----
    for (int idx = tid; idx < Nc * Hc; idx += T) {
        int row = idx >> 7, c2 = idx & 127;
        s_mb[row * ROWP + c2] = f2bf(nodes_b[idx]);   // cat tail (messages dead)
    }
    __syncthreads();
    float psum = 0.f;
    {
        float bgv = bg[col], bov = bo[col];
#pragma unroll 1
        for (int mt = 0; mt < 3; ++mt) {
            floatx4 ga = {0.f,0.f,0.f,0.f}, oa = {0.f,0.f,0.f,0.f};
#pragma unroll 1
            for (int kt = 0; kt < 8; ++kt) {
                short8 a = (kt < 4) ? afrag(hb_cur, mt, kt, lane) : afrag(s_mb, mt, kt - 4, lane);
                ga = mm(a, bfrag(wWg, wave, 8, kt, lane), ga);
                oa = mm(a, bfrag(wWo, wave, 8, kt, lane), oa);
            }
#pragma unroll
            for (int reg = 0; reg < 4; ++reg) {
                int row = mt * 16 + quad * 4 + reg;
                if (row < Nc && s_cnt[row] > 0)
                    psum += fast_sigmoid(ga[reg] + bgv) * (oa[reg] + bov);
            }
        }
    }
    psum += __shfl_xor(psum, 16);   // reduce the 4 quads sharing this col
    psum += __shfl_xor(psum, 32);
    if (quad == 0) out[(size_t)b * OUTc + col] = psum;
}

extern "C" void kernel_launch(void* const* d_in, const int* in_sizes, int n_in,
                              void* d_out, int out_size, void* d_ws, size_t ws_size,
                              hipStream_t stream) {
    const float* nodes = (const float*)d_in[0];
    const float* edges = (const float*)d_in[1];
    const float* We = (const float*)d_in[2];
    const float* Wn = (const float*)d_in[3];
    const float* Wm = (const float*)d_in[4];
    const float* Wi = (const float*)d_in[5];
    const float* Wh = (const float*)d_in[6];
    const float* bi = (const float*)d_in[7];
    const float* bh = (const float*)d_in[8];
    const float* Wg = (const float*)d_in[9];
    const float* bg = (const float*)d_in[10];
    const float* Wo = (const float*)d_in[11];
    const float* bo = (const float*)d_in[12];
    float* out = (float*)d_out;
    unsigned short* ws = (unsigned short*)d_ws;

    prep_kernel<<<384, 64, 0, stream>>>(Wn, Wm, Wi, Wh, Wg, Wo, ws);
    mpnn_kernel<<<Bc, T, 0, stream>>>(nodes, edges, We, bi, bh, bg, bo, ws, out);
}

// Round 16
// 251.374 us; speedup vs baseline: 2.1291x; 2.1291x over previous
//
#include <hip/hip_runtime.h>

#define T 512
constexpr int Bc = 512, Nc = 40, Hc = 128, FEc = 16, Mc = 128, OUTc = 128, NPASS = 3;
constexpr int ROWP = 136;   // bf16 LDS row pitch (MFMA A buffers: aligned b128 reads)
constexpr int NPP  = 132;   // scalar-access row pitch (np fp32 / emb bf16 / r / z)
constexpr int EPOOL = 512;  // LDS edge pool slots (mean ~296; fallback covers overflow)

typedef __attribute__((ext_vector_type(8))) short short8;
typedef __attribute__((ext_vector_type(4))) float floatx4;
typedef __attribute__((ext_vector_type(4))) float fvec4;
typedef _Float16 half2v __attribute__((ext_vector_type(2)));
typedef _Float16 half8v __attribute__((ext_vector_type(8)));

// ws layout (bf16 elements): fragment-major B operands only (384 KB, L2-resident)
constexpr int WS_WN = 0, WS_WM = 16384, WS_WI = 32768, WS_WH = 81920, WS_WG = 131072, WS_WO = 163840;

__device__ __forceinline__ float fast_rcp(float x) { return __builtin_amdgcn_rcpf(x); }
__device__ __forceinline__ float fast_sigmoid(float x) { return fast_rcp(1.f + __expf(-x)); }
__device__ __forceinline__ float fast_tanh(float x) {
    float t = __expf(2.f * x);
    return 1.f - 2.f * fast_rcp(t + 1.f);
}
__device__ __forceinline__ float bf2f(unsigned short u) {
    union { unsigned int i; float f; } v; v.i = ((unsigned int)u) << 16; return v.f;
}
__device__ __forceinline__ unsigned short f2bf(float f) {
    union { float f; unsigned int i; } v; v.f = f;
    unsigned int r = v.i + 0x7fff + ((v.i >> 16) & 1);   // RNE
    return (unsigned short)(r >> 16);
}
__device__ __forceinline__ half2v u2h(unsigned int u) {
    union { unsigned int i; half2v h; } v; v.i = u; return v.h;
}

__device__ __forceinline__ floatx4 mm(short8 a, short8 b, floatx4 c) {
    return __builtin_amdgcn_mfma_f32_16x16x32_bf16(a, b, c, 0, 0, 0);
}
// A-fragment: A[m=lane&15][k=quad*8+j]; rows>=40 clamped (their C rows discarded)
__device__ __forceinline__ short8 afrag(const unsigned short* buf, int mt, int kt, int lane) {
    int row = mt * 16 + (lane & 15); row = row > 39 ? 39 : row;
    return *(const short8*)(buf + row * ROWP + kt * 32 + (lane >> 4) * 8);
}
__device__ __forceinline__ short8 bfrag(const unsigned short* w, int nt, int nKT, int kt, int lane) {
    return *(const short8*)(w + ((nt * nKT + kt) * 64 + lane) * 8);
}

// ---- prep: weights -> bf16 B-fragment layout in ws ----
__global__ void prep_kernel(const float* __restrict__ Wn, const float* __restrict__ Wm,
                            const float* __restrict__ Wi, const float* __restrict__ Wh,
                            const float* __restrict__ Wg, const float* __restrict__ Wo,
                            unsigned short* __restrict__ ws) {
    int c = blockIdx.x, lane = threadIdx.x;
    int quad = lane >> 4, l16 = lane & 15;
    const float* W; int N, nKT, local; unsigned short* dst;
    if (c < 32)       { W = Wn; N = 128; nKT = 4; local = c;       dst = ws + WS_WN; }
    else if (c < 64)  { W = Wm; N = 128; nKT = 4; local = c - 32;  dst = ws + WS_WM; }
    else if (c < 160) { W = Wi; N = 384; nKT = 4; local = c - 64;  dst = ws + WS_WI; }
    else if (c < 256) { W = Wh; N = 384; nKT = 4; local = c - 160; dst = ws + WS_WH; }
    else if (c < 320) { W = Wg; N = 128; nKT = 8; local = c - 256; dst = ws + WS_WG; }
    else              { W = Wo; N = 128; nKT = 8; local = c - 320; dst = ws + WS_WO; }
    int nt = local / nKT, kt = local % nKT;
    short8 v;
#pragma unroll
    for (int j = 0; j < 8; ++j) {
        int k = kt * 32 + quad * 8 + j;
        v[j] = (short)f2bf(W[k * N + nt * 16 + l16]);
    }
    *(short8*)(dst + local * 512 + lane * 8) = v;
}

// T=512, 8 waves, LDS ~73 KB -> 2 blocks/CU.
// Anti-spill rules (R9/R10/R12, R15 lesson reinforced): attention reads LDS only; GEMM
// kt loops unroll 1 with inline bfrag (no hoist); no per-thread state across barriers;
// private arrays ONLY in fully-unrolled code (R15's serial sort w/ dynamic private
// array = scratch disaster). R16 = R12 + s_jo offset table (np & emb both pitch 132,
// proven conflict-free in R14) — drops the s_nbr-load->mul chain from the hot loop.
__global__ __launch_bounds__(T, 4) void mpnn_kernel(
    const float* __restrict__ nodes, const float* __restrict__ edges,
    const float* __restrict__ We, const float* __restrict__ bi,
    const float* __restrict__ bh, const float* __restrict__ bg,
    const float* __restrict__ bo, const unsigned short* __restrict__ ws,
    float* __restrict__ out)
{
    __shared__ __attribute__((aligned(16))) unsigned short s_hb[Nc * ROWP];   // bf16 h (MFMA A)
    __shared__ __attribute__((aligned(16))) unsigned short s_mb[Nc * ROWP];   // messages / nodes(cat) (MFMA A)
    __shared__ __attribute__((aligned(16))) float s_np[Nc * NPP];             // np fp32, then r (init: slot_src)
    __shared__ __attribute__((aligned(16))) unsigned short s_ebb[Nc * NPP];   // emb bf16, then z
    __shared__ __attribute__((aligned(16))) _Float16 s_poolh[EPOOL * FEc];    // 16 KB f16 edge features
    __shared__ unsigned short s_jo[EPOOL];   // per-slot j*NPP (element offset for np/emb)
    __shared__ unsigned char s_nbr[Nc][Nc];
    __shared__ int s_cnt[Nc];
    __shared__ int s_off[Nc];
    __shared__ int s_total;

    const int b = blockIdx.x, tid = threadIdx.x;
    const int lane = tid & 63, wave = tid >> 6;          // 8 waves; nt = wave
    const int quad = lane >> 4, l16 = lane & 15;
    const int m = tid & 127, g = tid >> 7;               // attention: g in 0..3
    const int col = wave * 16 + l16;

    const float* nodes_b = nodes + (size_t)b * Nc * Hc;
    const float* edges_b = edges + (size_t)b * Nc * Nc * FEc;
    const unsigned short* wWn = ws + WS_WN; const unsigned short* wWm = ws + WS_WM;
    const unsigned short* wWi = ws + WS_WI; const unsigned short* wWh = ws + WS_WH;
    const unsigned short* wWg = ws + WS_WG; const unsigned short* wWo = ws + WS_WO;

    // ---- init: h fp32 in registers (static map, fully unrolled), bf16 in LDS ----
    float hreg[3][4];
#pragma unroll
    for (int mt = 0; mt < 3; ++mt)
#pragma unroll
        for (int reg = 0; reg < 4; ++reg) {
            int row = mt * 16 + quad * 4 + reg;
            float v = (row < Nc) ? nodes_b[row * Hc + col] : 0.f;
            hreg[mt][reg] = v;
            if (row < Nc) s_hb[row * ROWP + col] = f2bf(v);
        }
    // ---- adjacency scan (streaming, non-temporal) ----
    for (int p = tid; p < Nc * Nc; p += T) {
        const fvec4* e4 = (const fvec4*)(edges_b + p * FEc);
        fvec4 a0 = __builtin_nontemporal_load(e4);
        fvec4 a1 = __builtin_nontemporal_load(e4 + 1);
        fvec4 a2 = __builtin_nontemporal_load(e4 + 2);
        fvec4 a3 = __builtin_nontemporal_load(e4 + 3);
        float s = a0.x + a0.y + a0.z + a0.w + a1.x + a1.y + a1.z + a1.w
                + a2.x + a2.y + a2.z + a2.w + a3.x + a3.y + a3.z + a3.w;
        ((unsigned char*)s_nbr)[p] = (s > 0.f) ? 1 : 0;
    }
    __syncthreads();
    if (tid < Nc) {               // compact neighbor list in place
        int c = 0;
#pragma unroll 1
        for (int j = 0; j < Nc; ++j)
            if (s_nbr[tid][j]) { s_nbr[tid][c] = (unsigned char)j; ++c; }
        s_cnt[tid] = c;
    }
    __syncthreads();
    if (tid == 0) {
        int tot = 0;
#pragma unroll 1
        for (int i = 0; i < Nc; ++i) { s_off[i] = tot; tot += s_cnt[i]; }
        s_total = tot;
    }
    __syncthreads();
    int* slot_src = (int*)s_np;   // temp alias; dead before pass-0 Phase A writes s_np
    if (tid < Nc) {
        int base = s_off[tid], cnt = s_cnt[tid];
#pragma unroll 1
        for (int kn = 0; kn < cnt; ++kn) {
            int slot = base + kn;
            if (slot < EPOOL) {
                int j = s_nbr[tid][kn];
                slot_src[slot] = tid * Nc + j;
                s_jo[slot] = (unsigned short)(j * NPP);
            }
        }
    }
    __syncthreads();
    {   // fill compact f16 edge pool (once; reused all 3 passes)
        const int E = s_total < EPOOL ? s_total : EPOOL;
#pragma unroll 1
        for (int w = tid; w < E * 2; w += T) {
            int s = w >> 1, hf = w & 1;
            const float* src = edges_b + (size_t)slot_src[s] * FEc + hf * 8;
            fvec4 x = __builtin_nontemporal_load((const fvec4*)src);
            fvec4 y = __builtin_nontemporal_load((const fvec4*)(src + 4));
            half8v v;
            v[0] = (_Float16)x.x; v[1] = (_Float16)x.y; v[2] = (_Float16)x.z; v[3] = (_Float16)x.w;
            v[4] = (_Float16)y.x; v[5] = (_Float16)y.y; v[6] = (_Float16)y.z; v[7] = (_Float16)y.w;
            *(half8v*)(s_poolh + s * FEc + hf * 8) = v;
        }
    }
    __syncthreads();

    for (int pass = 0; pass < NPASS; ++pass) {
        // ---- Phase A: np = h@Wn (fp32), emb = h@Wm (bf16) ----
#pragma unroll 1
        for (int jb = 0; jb < 2; ++jb) {
            const unsigned short* wb = jb ? wWm : wWn;
            short8 bfr[4];
#pragma unroll
            for (int kt = 0; kt < 4; ++kt) bfr[kt] = bfrag(wb, wave, 4, kt, lane);
#pragma unroll 1
            for (int mt = 0; mt < 3; ++mt) {
                floatx4 acc = {0.f, 0.f, 0.f, 0.f};
#pragma unroll
                for (int kt = 0; kt < 4; ++kt) acc = mm(afrag(s_hb, mt, kt, lane), bfr[kt], acc);
#pragma unroll
                for (int reg = 0; reg < 4; ++reg) {
                    int row = mt * 16 + quad * 4 + reg;
                    if (row < Nc) {
                        if (jb) s_ebb[row * NPP + col] = f2bf(acc[reg]);
                        else    s_np[row * NPP + col] = acc[reg];
                    }
                }
            }
        }
        __syncthreads();

        // ---- Attention: f16 pool + fdot2, jo-table addressing ----
        {
#if __has_builtin(__builtin_amdgcn_fdot2)
            half2v wh[8];
#pragma unroll
            for (int f = 0; f < 8; ++f)
                wh[f] = (half2v){(_Float16)We[(2 * f) * Mc + m], (_Float16)We[(2 * f + 1) * Mc + m]};
#else
            float wef[FEc];
#pragma unroll
            for (int f = 0; f < FEc; ++f) wef[f] = We[f * Mc + m];
#endif
#pragma unroll 1
            for (int ib = 0; ib < 10; ++ib) {
                int i = g + ib * 4;
                int cnt = s_cnt[i], base = s_off[i];
                int cap = EPOOL - base; if (cap > cnt) cap = cnt; if (cap < 0) cap = 0;
                float pden = 0.f, pnum = 0.f;
#pragma unroll 1
                for (int s = base; s < base + cap; ++s) {
                    const uint4* e = (const uint4*)(s_poolh + s * FEc);
                    uint4 p0 = e[0], p1 = e[1];
                    int jo = s_jo[s];
                    float np = s_np[jo + m];
                    float em = bf2f(s_ebb[jo + m]);
#if __has_builtin(__builtin_amdgcn_fdot2)
                    float ep = 0.f;
                    ep = __builtin_amdgcn_fdot2(u2h(p0.x), wh[0], ep, false);
                    ep = __builtin_amdgcn_fdot2(u2h(p0.y), wh[1], ep, false);
                    ep = __builtin_amdgcn_fdot2(u2h(p0.z), wh[2], ep, false);
                    ep = __builtin_amdgcn_fdot2(u2h(p0.w), wh[3], ep, false);
                    ep = __builtin_amdgcn_fdot2(u2h(p1.x), wh[4], ep, false);
                    ep = __builtin_amdgcn_fdot2(u2h(p1.y), wh[5], ep, false);
                    ep = __builtin_amdgcn_fdot2(u2h(p1.z), wh[6], ep, false);
                    ep = __builtin_amdgcn_fdot2(u2h(p1.w), wh[7], ep, false);
#else
                    half2v h0 = u2h(p0.x), h1 = u2h(p0.y), h2 = u2h(p0.z), h3 = u2h(p0.w);
                    half2v h4 = u2h(p1.x), h5 = u2h(p1.y), h6 = u2h(p1.z), h7 = u2h(p1.w);
                    float ep = (float)h0.x*wef[0] + (float)h0.y*wef[1] + (float)h1.x*wef[2] + (float)h1.y*wef[3]
                             + (float)h2.x*wef[4] + (float)h2.y*wef[5] + (float)h3.x*wef[6] + (float)h3.y*wef[7]
                             + (float)h4.x*wef[8] + (float)h4.y*wef[9] + (float)h5.x*wef[10]+ (float)h5.y*wef[11]
                             + (float)h6.x*wef[12]+ (float)h6.y*wef[13]+ (float)h7.x*wef[14]+ (float)h7.y*wef[15];
#endif
                    float w = __expf(fast_tanh(ep + np));   // logits in (-1,1): no max-sub
                    pden += w;
                    pnum += w * em;
                }
#pragma unroll 1
                for (int kn = cap; kn < cnt; ++kn) {   // pool-overflow tail (statistically never)
                    int j = s_nbr[i][kn];
                    const float4* ef = (const float4*)(edges_b + ((size_t)i * Nc + j) * FEc);
                    float4 a0 = ef[0], a1 = ef[1], a2 = ef[2], a3 = ef[3];
                    float ep = a0.x*We[0*Mc+m] + a0.y*We[1*Mc+m] + a0.z*We[2*Mc+m] + a0.w*We[3*Mc+m]
                             + a1.x*We[4*Mc+m] + a1.y*We[5*Mc+m] + a1.z*We[6*Mc+m] + a1.w*We[7*Mc+m]
                             + a2.x*We[8*Mc+m] + a2.y*We[9*Mc+m] + a2.z*We[10*Mc+m]+ a2.w*We[11*Mc+m]
                             + a3.x*We[12*Mc+m]+ a3.y*We[13*Mc+m]+ a3.z*We[14*Mc+m]+ a3.w*We[15*Mc+m];
                    float np = s_np[j * NPP + m];
                    float em = bf2f(s_ebb[j * NPP + m]);
                    float w = __expf(fast_tanh(ep + np));
                    pden += w;
                    pnum += w * em;
                }
                s_mb[i * ROWP + m] = f2bf((cnt > 0) ? pnum * fast_rcp(pden) : 0.f);
            }
        }
        __syncthreads();

        // ---- GRU alpha: r (fp32 s_np), z (bf16 s_ebb); inline bfrag, 1 acc set ----
#pragma unroll 1
        for (int grp = 0; grp < 2; ++grp) {
            float bb = bi[grp * 128 + col] + bh[grp * 128 + col];
#pragma unroll 1
            for (int mt = 0; mt < 3; ++mt) {
                floatx4 acc = {0.f,0.f,0.f,0.f};
#pragma unroll 1
                for (int kt = 0; kt < 4; ++kt) {
                    acc = mm(afrag(s_mb, mt, kt, lane), bfrag(wWi, grp * 8 + wave, 4, kt, lane), acc);
                    acc = mm(afrag(s_hb, mt, kt, lane), bfrag(wWh, grp * 8 + wave, 4, kt, lane), acc);
                }
#pragma unroll
                for (int reg = 0; reg < 4; ++reg) {
                    int row = mt * 16 + quad * 4 + reg;
                    if (row < Nc) {
                        float sg = fast_sigmoid(acc[reg] + bb);
                        if (grp) s_ebb[row * NPP + col] = f2bf(sg);
                        else     s_np[row * NPP + col] = sg;
                    }
                }
            }
        }
        // ---- GRU beta: candidate + h update into hreg (same-thread r/z) ----
        {
            float bnI = bi[256 + col], bnH = bh[256 + col];
#pragma unroll
            for (int mt = 0; mt < 3; ++mt) {
                floatx4 ai = {0.f,0.f,0.f,0.f}, ah = {0.f,0.f,0.f,0.f};
#pragma unroll 1
                for (int kt = 0; kt < 4; ++kt) {
                    ai = mm(afrag(s_mb, mt, kt, lane), bfrag(wWi, 16 + wave, 4, kt, lane), ai);
                    ah = mm(afrag(s_hb, mt, kt, lane), bfrag(wWh, 16 + wave, 4, kt, lane), ah);
                }
#pragma unroll
                for (int reg = 0; reg < 4; ++reg) {
                    int row = mt * 16 + quad * 4 + reg;
                    if (row < Nc) {
                        float hold = hreg[mt][reg];
                        float r = s_np[row * NPP + col];
                        float z = bf2f(s_ebb[row * NPP + col]);
                        float n = fast_tanh(ai[reg] + bnI + r * (ah[reg] + bnH));
                        float v = (1.f - z) * n + z * hold;
                        hreg[mt][reg] = (s_cnt[row] > 0) ? v : hold;
                    }
                }
            }
        }
        __syncthreads();   // all afrag reads of s_hb complete before overwrite
#pragma unroll
        for (int mt = 0; mt < 3; ++mt)
#pragma unroll
            for (int reg = 0; reg < 4; ++reg) {
                int row = mt * 16 + quad * 4 + reg;
                if (row < Nc) s_hb[row * ROWP + col] = f2bf(hreg[mt][reg]);
            }
        __syncthreads();
    }

    // ---- Readout: out = sum_i mask * sigmoid(cat@Wg+bg) * (cat@Wo+bo) ----
    for (int idx = tid; idx < Nc * Hc; idx += T) {
        int row = idx >> 7, c2 = idx & 127;
        s_mb[row * ROWP + c2] = f2bf(nodes_b[idx]);   // cat tail (messages dead)
    }
    __syncthreads();
    float psum = 0.f;
    {
        float bgv = bg[col], bov = bo[col];
#pragma unroll 1
        for (int mt = 0; mt < 3; ++mt) {
            floatx4 ga = {0.f,0.f,0.f,0.f}, oa = {0.f,0.f,0.f,0.f};
#pragma unroll 1
            for (int kt = 0; kt < 8; ++kt) {
                short8 a = (kt < 4) ? afrag(s_hb, mt, kt, lane) : afrag(s_mb, mt, kt - 4, lane);
                ga = mm(a, bfrag(wWg, wave, 8, kt, lane), ga);
                oa = mm(a, bfrag(wWo, wave, 8, kt, lane), oa);
            }
#pragma unroll
            for (int reg = 0; reg < 4; ++reg) {
                int row = mt * 16 + quad * 4 + reg;
                if (row < Nc && s_cnt[row] > 0)
                    psum += fast_sigmoid(ga[reg] + bgv) * (oa[reg] + bov);
            }
        }
    }
    psum += __shfl_xor(psum, 16);   // reduce the 4 quads sharing this col
    psum += __shfl_xor(psum, 32);
    if (quad == 0) out[(size_t)b * OUTc + col] = psum;
}

extern "C" void kernel_launch(void* const* d_in, const int* in_sizes, int n_in,
                              void* d_out, int out_size, void* d_ws, size_t ws_size,
                              hipStream_t stream) {
    const float* nodes = (const float*)d_in[0];
    const float* edges = (const float*)d_in[1];
    const float* We = (const float*)d_in[2];
    const float* Wn = (const float*)d_in[3];
    const float* Wm = (const float*)d_in[4];
    const float* Wi = (const float*)d_in[5];
    const float* Wh = (const float*)d_in[6];
    const float* bi = (const float*)d_in[7];
    const float* bh = (const float*)d_in[8];
    const float* Wg = (const float*)d_in[9];
    const float* bg = (const float*)d_in[10];
    const float* Wo = (const float*)d_in[11];
    const float* bo = (const float*)d_in[12];
    float* out = (float*)d_out;
    unsigned short* ws = (unsigned short*)d_ws;

    prep_kernel<<<384, 64, 0, stream>>>(Wn, Wm, Wi, Wh, Wg, Wo, ws);
    mpnn_kernel<<<Bc, T, 0, stream>>>(nodes, edges, We, bi, bh, bg, bo, ws, out);
}

// Round 17
// 245.736 us; speedup vs baseline: 2.1780x; 1.0229x over previous
//
#include <hip/hip_runtime.h>

#define T 512
constexpr int Bc = 512, Nc = 40, Hc = 128, FEc = 16, Mc = 128, OUTc = 128, NPASS = 3;
constexpr int ROWP = 136;   // bf16 LDS row pitch
constexpr int NPP  = 132;   // fp32 np/r row pitch (2-way bank alias on reads/writes: free)
constexpr int EPOOL = 512;  // LDS edge pool slots (mean ~296; fallback covers overflow)

typedef __attribute__((ext_vector_type(8))) short short8;
typedef __attribute__((ext_vector_type(4))) float floatx4;
typedef __attribute__((ext_vector_type(4))) float fvec4;
typedef _Float16 half2v __attribute__((ext_vector_type(2)));
typedef _Float16 half8v __attribute__((ext_vector_type(8)));

// ws layout (bf16 elements): fragment-major B operands only (384 KB, L2-resident)
constexpr int WS_WN = 0, WS_WM = 16384, WS_WI = 32768, WS_WH = 81920, WS_WG = 131072, WS_WO = 163840;

__device__ __forceinline__ float fast_rcp(float x) { return __builtin_amdgcn_rcpf(x); }
__device__ __forceinline__ float fast_sigmoid(float x) { return fast_rcp(1.f + __expf(-x)); }
__device__ __forceinline__ float fast_tanh(float x) {
    float t = __expf(2.f * x);
    return 1.f - 2.f * fast_rcp(t + 1.f);
}
__device__ __forceinline__ float bf2f(unsigned short u) {
    union { unsigned int i; float f; } v; v.i = ((unsigned int)u) << 16; return v.f;
}
__device__ __forceinline__ unsigned short f2bf(float f) {
    union { float f; unsigned int i; } v; v.f = f;
    unsigned int r = v.i + 0x7fff + ((v.i >> 16) & 1);   // RNE
    return (unsigned short)(r >> 16);
}
__device__ __forceinline__ half2v u2h(unsigned int u) {
    union { unsigned int i; half2v h; } v; v.i = u; return v.h;
}

__device__ __forceinline__ floatx4 mm(short8 a, short8 b, floatx4 c) {
    return __builtin_amdgcn_mfma_f32_16x16x32_bf16(a, b, c, 0, 0, 0);
}
// A-fragment: A[m=lane&15][k=quad*8+j]; rows>=40 clamped (their C rows discarded)
__device__ __forceinline__ short8 afrag(const unsigned short* buf, int mt, int kt, int lane) {
    int row = mt * 16 + (lane & 15); row = row > 39 ? 39 : row;
    return *(const short8*)(buf + row * ROWP + kt * 32 + (lane >> 4) * 8);
}
__device__ __forceinline__ short8 bfrag(const unsigned short* w, int nt, int nKT, int kt, int lane) {
    return *(const short8*)(w + ((nt * nKT + kt) * 64 + lane) * 8);
}

// ---- prep: weights -> bf16 B-fragment layout in ws ----
__global__ void prep_kernel(const float* __restrict__ Wn, const float* __restrict__ Wm,
                            const float* __restrict__ Wi, const float* __restrict__ Wh,
                            const float* __restrict__ Wg, const float* __restrict__ Wo,
                            unsigned short* __restrict__ ws) {
    int c = blockIdx.x, lane = threadIdx.x;
    int quad = lane >> 4, l16 = lane & 15;
    const float* W; int N, nKT, local; unsigned short* dst;
    if (c < 32)       { W = Wn; N = 128; nKT = 4; local = c;       dst = ws + WS_WN; }
    else if (c < 64)  { W = Wm; N = 128; nKT = 4; local = c - 32;  dst = ws + WS_WM; }
    else if (c < 160) { W = Wi; N = 384; nKT = 4; local = c - 64;  dst = ws + WS_WI; }
    else if (c < 256) { W = Wh; N = 384; nKT = 4; local = c - 160; dst = ws + WS_WH; }
    else if (c < 320) { W = Wg; N = 128; nKT = 8; local = c - 256; dst = ws + WS_WG; }
    else              { W = Wo; N = 128; nKT = 8; local = c - 320; dst = ws + WS_WO; }
    int nt = local / nKT, kt = local % nKT;
    short8 v;
#pragma unroll
    for (int j = 0; j < 8; ++j) {
        int k = kt * 32 + quad * 8 + j;
        v[j] = (short)f2bf(W[k * N + nt * 16 + l16]);
    }
    *(short8*)(dst + local * 512 + lane * 8) = v;
}

// T=512, 8 waves, LDS ~70 KB -> 2 blocks/CU (4 waves/SIMD).
// R9/R10/R12-proven anti-spill rules: (1) attention reads LDS pool only; (2) GEMM mt/kt
// loops `unroll 1`; (3) private arrays only in fully-unrolled code; (4) no per-thread
// state persists across barriers. Pool in f16 + v_dot2_f32_f16 (8 inst for the
// 16-term ep dot), np & r-gate fp32 in LDS (no pack/unpack; they never feed MFMA).
// R17 = byte-exact R12: best verified state (157 us kernel). R13-R16 variants
// (pair-interleave, jo-table, hoist, unroll-2, LPT, h-dbuf) all neutral or regressed —
// structure is latency-plateaued (VALU 48%, MFMA 6%, HBM 5%, occupancy grid-capped).
__global__ __launch_bounds__(T, 4) void mpnn_kernel(
    const float* __restrict__ nodes, const float* __restrict__ edges,
    const float* __restrict__ We, const float* __restrict__ bi,
    const float* __restrict__ bh, const float* __restrict__ bg,
    const float* __restrict__ bo, const unsigned short* __restrict__ ws,
    float* __restrict__ out)
{
    __shared__ __attribute__((aligned(16))) unsigned short s_hb[Nc * ROWP];   // bf16 h
    __shared__ __attribute__((aligned(16))) unsigned short s_mb[Nc * ROWP];   // messages / nodes(cat)
    __shared__ __attribute__((aligned(16))) float s_np[Nc * NPP];             // np fp32, then r-gate fp32
    __shared__ __attribute__((aligned(16))) unsigned short s_eb[Nc * ROWP];   // emb, then z (init: slot_src)
    __shared__ __attribute__((aligned(16))) _Float16 s_poolh[EPOOL * FEc];    // 16 KB f16 edge features
    __shared__ unsigned char s_nbr[Nc][Nc];
    __shared__ int s_cnt[Nc];
    __shared__ int s_off[Nc];
    __shared__ int s_total;

    const int b = blockIdx.x, tid = threadIdx.x;
    const int lane = tid & 63, wave = tid >> 6;          // 8 waves; nt = wave
    const int quad = lane >> 4, l16 = lane & 15;
    const int m = tid & 127, g = tid >> 7;               // attention: g in 0..3
    const int col = wave * 16 + l16;

    const float* nodes_b = nodes + (size_t)b * Nc * Hc;
    const float* edges_b = edges + (size_t)b * Nc * Nc * FEc;
    const unsigned short* wWn = ws + WS_WN; const unsigned short* wWm = ws + WS_WM;
    const unsigned short* wWi = ws + WS_WI; const unsigned short* wWh = ws + WS_WH;
    const unsigned short* wWg = ws + WS_WG; const unsigned short* wWo = ws + WS_WO;

    // ---- init: h fp32 in registers (static map, fully unrolled), bf16 in LDS ----
    float hreg[3][4];
#pragma unroll
    for (int mt = 0; mt < 3; ++mt)
#pragma unroll
        for (int reg = 0; reg < 4; ++reg) {
            int row = mt * 16 + quad * 4 + reg;
            float v = (row < Nc) ? nodes_b[row * Hc + col] : 0.f;
            hreg[mt][reg] = v;
            if (row < Nc) s_hb[row * ROWP + col] = f2bf(v);
        }
    // ---- adjacency scan (streaming, non-temporal) ----
    for (int p = tid; p < Nc * Nc; p += T) {
        const fvec4* e4 = (const fvec4*)(edges_b + p * FEc);
        fvec4 a0 = __builtin_nontemporal_load(e4);
        fvec4 a1 = __builtin_nontemporal_load(e4 + 1);
        fvec4 a2 = __builtin_nontemporal_load(e4 + 2);
        fvec4 a3 = __builtin_nontemporal_load(e4 + 3);
        float s = a0.x + a0.y + a0.z + a0.w + a1.x + a1.y + a1.z + a1.w
                + a2.x + a2.y + a2.z + a2.w + a3.x + a3.y + a3.z + a3.w;
        ((unsigned char*)s_nbr)[p] = (s > 0.f) ? 1 : 0;
    }
    __syncthreads();
    if (tid < Nc) {               // compact neighbor list in place
        int c = 0;
#pragma unroll 1
        for (int j = 0; j < Nc; ++j)
            if (s_nbr[tid][j]) { s_nbr[tid][c] = (unsigned char)j; ++c; }
        s_cnt[tid] = c;
    }
    __syncthreads();
    if (tid == 0) {
        int tot = 0;
#pragma unroll 1
        for (int i = 0; i < Nc; ++i) { s_off[i] = tot; tot += s_cnt[i]; }
        s_total = tot;
    }
    __syncthreads();
    int* slot_src = (int*)s_eb;   // temp alias; dead before pass-0 Phase A writes s_eb
    if (tid < Nc) {
        int base = s_off[tid], cnt = s_cnt[tid];
#pragma unroll 1
        for (int kn = 0; kn < cnt; ++kn) {
            int slot = base + kn;
            if (slot < EPOOL) slot_src[slot] = tid * Nc + s_nbr[tid][kn];
        }
    }
    __syncthreads();
    {   // fill compact f16 edge pool (once; reused all 3 passes)
        const int E = s_total < EPOOL ? s_total : EPOOL;
#pragma unroll 1
        for (int w = tid; w < E * 2; w += T) {
            int s = w >> 1, hf = w & 1;
            const float* src = edges_b + (size_t)slot_src[s] * FEc + hf * 8;
            fvec4 x = __builtin_nontemporal_load((const fvec4*)src);
            fvec4 y = __builtin_nontemporal_load((const fvec4*)(src + 4));
            half8v v;
            v[0] = (_Float16)x.x; v[1] = (_Float16)x.y; v[2] = (_Float16)x.z; v[3] = (_Float16)x.w;
            v[4] = (_Float16)y.x; v[5] = (_Float16)y.y; v[6] = (_Float16)y.z; v[7] = (_Float16)y.w;
            *(half8v*)(s_poolh + s * FEc + hf * 8) = v;
        }
    }
    __syncthreads();

    for (int pass = 0; pass < NPASS; ++pass) {
        // ---- Phase A: np = h@Wn (fp32 out), emb = h@Wm (bf16 out) ----
#pragma unroll 1
        for (int jb = 0; jb < 2; ++jb) {
            const unsigned short* wb = jb ? wWm : wWn;
            short8 bfr[4];
#pragma unroll
            for (int kt = 0; kt < 4; ++kt) bfr[kt] = bfrag(wb, wave, 4, kt, lane);
#pragma unroll 1
            for (int mt = 0; mt < 3; ++mt) {
                floatx4 acc = {0.f, 0.f, 0.f, 0.f};
#pragma unroll
                for (int kt = 0; kt < 4; ++kt) acc = mm(afrag(s_hb, mt, kt, lane), bfr[kt], acc);
#pragma unroll
                for (int reg = 0; reg < 4; ++reg) {
                    int row = mt * 16 + quad * 4 + reg;
                    if (row < Nc) {
                        if (jb) s_eb[row * ROWP + col] = f2bf(acc[reg]);
                        else    s_np[row * NPP + col] = acc[reg];
                    }
                }
            }
        }
        __syncthreads();

        // ---- Attention: f16 pool + v_dot2_f32_f16 (~22 inst/edge) ----
        {
#if __has_builtin(__builtin_amdgcn_fdot2)
            half2v wh[8];
#pragma unroll
            for (int f = 0; f < 8; ++f)
                wh[f] = (half2v){(_Float16)We[(2 * f) * Mc + m], (_Float16)We[(2 * f + 1) * Mc + m]};
#else
            float wef[FEc];
#pragma unroll
            for (int f = 0; f < FEc; ++f) wef[f] = We[f * Mc + m];
#endif
#pragma unroll 1
            for (int ib = 0; ib < 10; ++ib) {
                int i = g + ib * 4;
                int cnt = s_cnt[i], base = s_off[i];
                int cap = EPOOL - base; if (cap > cnt) cap = cnt; if (cap < 0) cap = 0;
                float pden = 0.f, pnum = 0.f;
                int kn = 0;
#pragma unroll 1
                for (; kn < cap; ++kn) {
                    int j = s_nbr[i][kn];
                    const uint4* e = (const uint4*)(s_poolh + (base + kn) * FEc);
                    uint4 p0 = e[0], p1 = e[1];
#if __has_builtin(__builtin_amdgcn_fdot2)
                    float ep = 0.f;
                    ep = __builtin_amdgcn_fdot2(u2h(p0.x), wh[0], ep, false);
                    ep = __builtin_amdgcn_fdot2(u2h(p0.y), wh[1], ep, false);
                    ep = __builtin_amdgcn_fdot2(u2h(p0.z), wh[2], ep, false);
                    ep = __builtin_amdgcn_fdot2(u2h(p0.w), wh[3], ep, false);
                    ep = __builtin_amdgcn_fdot2(u2h(p1.x), wh[4], ep, false);
                    ep = __builtin_amdgcn_fdot2(u2h(p1.y), wh[5], ep, false);
                    ep = __builtin_amdgcn_fdot2(u2h(p1.z), wh[6], ep, false);
                    ep = __builtin_amdgcn_fdot2(u2h(p1.w), wh[7], ep, false);
#else
                    half2v h0 = u2h(p0.x), h1 = u2h(p0.y), h2 = u2h(p0.z), h3 = u2h(p0.w);
                    half2v h4 = u2h(p1.x), h5 = u2h(p1.y), h6 = u2h(p1.z), h7 = u2h(p1.w);
                    float ep = (float)h0.x*wef[0] + (float)h0.y*wef[1] + (float)h1.x*wef[2] + (float)h1.y*wef[3]
                             + (float)h2.x*wef[4] + (float)h2.y*wef[5] + (float)h3.x*wef[6] + (float)h3.y*wef[7]
                             + (float)h4.x*wef[8] + (float)h4.y*wef[9] + (float)h5.x*wef[10]+ (float)h5.y*wef[11]
                             + (float)h6.x*wef[12]+ (float)h6.y*wef[13]+ (float)h7.x*wef[14]+ (float)h7.y*wef[15];
#endif
                    float x = ep + s_np[j * NPP + m];
                    float w = __expf(fast_tanh(x));   // logits in (-1,1): no max-sub needed
                    pden += w;
                    pnum += w * bf2f(s_eb[j * ROWP + m]);
                }
#pragma unroll 1
                for (; kn < cnt; ++kn) {   // pool-overflow tail (statistically never)
                    int j = s_nbr[i][kn];
                    const float4* ef = (const float4*)(edges_b + ((size_t)i * Nc + j) * FEc);
                    float4 a0 = ef[0], a1 = ef[1], a2 = ef[2], a3 = ef[3];
                    float ep = a0.x*We[0*Mc+m] + a0.y*We[1*Mc+m] + a0.z*We[2*Mc+m] + a0.w*We[3*Mc+m]
                             + a1.x*We[4*Mc+m] + a1.y*We[5*Mc+m] + a1.z*We[6*Mc+m] + a1.w*We[7*Mc+m]
                             + a2.x*We[8*Mc+m] + a2.y*We[9*Mc+m] + a2.z*We[10*Mc+m]+ a2.w*We[11*Mc+m]
                             + a3.x*We[12*Mc+m]+ a3.y*We[13*Mc+m]+ a3.z*We[14*Mc+m]+ a3.w*We[15*Mc+m];
                    float w = __expf(fast_tanh(ep + s_np[j * NPP + m]));
                    pden += w;
                    pnum += w * bf2f(s_eb[j * ROWP + m]);
                }
                s_mb[i * ROWP + m] = f2bf((cnt > 0) ? pnum * fast_rcp(pden) : 0.f);
            }
        }
        __syncthreads();

        // ---- GRU alpha: r (fp32 in s_np), z (bf16 in s_eb); 1 acc set live ----
#pragma unroll 1
        for (int grp = 0; grp < 2; ++grp) {
            float bb = bi[grp * 128 + col] + bh[grp * 128 + col];
#pragma unroll 1
            for (int mt = 0; mt < 3; ++mt) {
                floatx4 acc = {0.f,0.f,0.f,0.f};
#pragma unroll 1
                for (int kt = 0; kt < 4; ++kt) {
                    acc = mm(afrag(s_mb, mt, kt, lane), bfrag(wWi, grp * 8 + wave, 4, kt, lane), acc);
                    acc = mm(afrag(s_hb, mt, kt, lane), bfrag(wWh, grp * 8 + wave, 4, kt, lane), acc);
                }
#pragma unroll
                for (int reg = 0; reg < 4; ++reg) {
                    int row = mt * 16 + quad * 4 + reg;
                    if (row < Nc) {
                        float sg = fast_sigmoid(acc[reg] + bb);
                        if (grp) s_eb[row * ROWP + col] = f2bf(sg);
                        else     s_np[row * NPP + col] = sg;
                    }
                }
            }
        }
        // ---- GRU beta: candidate + h update into hreg (regs private -> pre-barrier ok) ----
        {
            float bnI = bi[256 + col], bnH = bh[256 + col];
#pragma unroll
            for (int mt = 0; mt < 3; ++mt) {
                floatx4 ai = {0.f,0.f,0.f,0.f}, ah = {0.f,0.f,0.f,0.f};
#pragma unroll 1
                for (int kt = 0; kt < 4; ++kt) {
                    ai = mm(afrag(s_mb, mt, kt, lane), bfrag(wWi, 16 + wave, 4, kt, lane), ai);
                    ah = mm(afrag(s_hb, mt, kt, lane), bfrag(wWh, 16 + wave, 4, kt, lane), ah);
                }
#pragma unroll
                for (int reg = 0; reg < 4; ++reg) {
                    int row = mt * 16 + quad * 4 + reg;
                    if (row < Nc) {
                        float hold = hreg[mt][reg];
                        float r = s_np[row * NPP + col];
                        float z = bf2f(s_eb[row * ROWP + col]);
                        float n = fast_tanh(ai[reg] + bnI + r * (ah[reg] + bnH));
                        float v = (1.f - z) * n + z * hold;
                        hreg[mt][reg] = (s_cnt[row] > 0) ? v : hold;
                    }
                }
            }
        }
        __syncthreads();   // all afrag reads of s_hb complete before overwrite
#pragma unroll
        for (int mt = 0; mt < 3; ++mt)
#pragma unroll
            for (int reg = 0; reg < 4; ++reg) {
                int row = mt * 16 + quad * 4 + reg;
                if (row < Nc) s_hb[row * ROWP + col] = f2bf(hreg[mt][reg]);
            }
        __syncthreads();
    }

    // ---- Readout: out = sum_i mask * sigmoid(cat@Wg+bg) * (cat@Wo+bo) ----
    for (int idx = tid; idx < Nc * Hc; idx += T) {
        int row = idx >> 7, c2 = idx & 127;
        s_mb[row * ROWP + c2] = f2bf(nodes_b[idx]);   // cat tail (messages dead)
    }
    __syncthreads();
    float psum = 0.f;
    {
        float bgv = bg[col], bov = bo[col];
#pragma unroll 1
        for (int mt = 0; mt < 3; ++mt) {
            floatx4 ga = {0.f,0.f,0.f,0.f}, oa = {0.f,0.f,0.f,0.f};
#pragma unroll 1
            for (int kt = 0; kt < 8; ++kt) {
                short8 a = (kt < 4) ? afrag(s_hb, mt, kt, lane) : afrag(s_mb, mt, kt - 4, lane);
                ga = mm(a, bfrag(wWg, wave, 8, kt, lane), ga);
                oa = mm(a, bfrag(wWo, wave, 8, kt, lane), oa);
            }
#pragma unroll
            for (int reg = 0; reg < 4; ++reg) {
                int row = mt * 16 + quad * 4 + reg;
                if (row < Nc && s_cnt[row] > 0)
                    psum += fast_sigmoid(ga[reg] + bgv) * (oa[reg] + bov);
            }
        }
    }
    psum += __shfl_xor(psum, 16);   // reduce the 4 quads sharing this col
    psum += __shfl_xor(psum, 32);
    if (quad == 0) out[(size_t)b * OUTc + col] = psum;
}

extern "C" void kernel_launch(void* const* d_in, const int* in_sizes, int n_in,
                              void* d_out, int out_size, void* d_ws, size_t ws_size,
                              hipStream_t stream) {
    const float* nodes = (const float*)d_in[0];
    const float* edges = (const float*)d_in[1];
    const float* We = (const float*)d_in[2];
    const float* Wn = (const float*)d_in[3];
    const float* Wm = (const float*)d_in[4];
    const float* Wi = (const float*)d_in[5];
    const float* Wh = (const float*)d_in[6];
    const float* bi = (const float*)d_in[7];
    const float* bh = (const float*)d_in[8];
    const float* Wg = (const float*)d_in[9];
    const float* bg = (const float*)d_in[10];
    const float* Wo = (const float*)d_in[11];
    const float* bo = (const float*)d_in[12];
    float* out = (float*)d_out;
    unsigned short* ws = (unsigned short*)d_ws;

    prep_kernel<<<384, 64, 0, stream>>>(Wn, Wm, Wi, Wh, Wg, Wo, ws);
    mpnn_kernel<<<Bc, T, 0, stream>>>(nodes, edges, We, bi, bh, bg, bo, ws, out);
}